// Round 5
// baseline (2896.778 us; speedup 1.0000x reference)
//
#include <hip/hip_runtime.h>
#include <math.h>

#define HH 512
#define LL 128
#define BB 4
#define TT 130            // L + 2
#define G4 2048           // 4*H

typedef float f32x4_ __attribute__((ext_vector_type(4)));

// ---- ws layout (float indices) ----
// HF: 131 slots of [B][H] = 131*2048 floats  (HF[s] = fwd state after consuming xs[0..s-1])
// HB: same                                   (HB[s] = bwd state after consuming xs[s..T-1])
// flags: int[2][131][32] (per-producer, per-slot readiness; written once each)
#define HF_OFF 0
#define HB_OFF 268288
#define FLG_OFF 536576
// xproj lives in the TAIL of d_out (K3 overwrites it last): 2 * 130*4*2048 floats
#define XPROJ_PER_DIR (TT * BB * G4)              // 1064960
#define XPROJ_OFF (67108864 - 2 * XPROJ_PER_DIR)  // 64978944

// ---------------- K0: zero the flag array (ws is poisoned 0xAA each launch) --
__global__ __launch_bounds__(256) void k0_init(float* ws) {
    int tid = threadIdx.x;
    int* flg = (int*)(ws + FLG_OFF);
    for (int i = tid; i < 2 * 131 * 32; i += 256) flg[i] = 0;
}

// ---------------- K1: input projection GEMM (both dirs) ----------------
__global__ __launch_bounds__(256) void k1_xproj(
    const float* __restrict__ wr,
    const float* __restrict__ WihF, const float* __restrict__ bF,
    const float* __restrict__ WihB, const float* __restrict__ bB,
    float* __restrict__ outbuf) {
    __shared__ float As[16][132];
    __shared__ float Bs[16][132];
    int bid = blockIdx.x;
    int d = bid / 80;
    int r2 = bid % 80;
    int mt = r2 >> 4, nt = r2 & 15;
    const float* Wih  = d ? WihB : WihF;
    const float* bias = d ? bB : bF;
    float* xp = outbuf + XPROJ_OFF + (size_t)d * XPROJ_PER_DIR;
    int tid = threadIdx.x;
    int ty = tid >> 4, tx = tid & 15;
    int m0 = mt * 128, n0 = nt * 128;

    float acc[8][8];
#pragma unroll
    for (int i = 0; i < 8; i++)
#pragma unroll
        for (int j = 0; j < 8; j++) acc[i][j] = 0.f;

    for (int k0 = 0; k0 < HH; k0 += 16) {
#pragma unroll
        for (int l = tid; l < 512; l += 256) {
            int rrow = l & 127;
            int kq = l >> 7;
            int m = m0 + rrow;
            int t = m >> 2, b = m & 3;
            float4 av = make_float4(0.f, 0.f, 0.f, 0.f);
            if (t >= 1 && t <= 128)
                av = *(const float4*)&wr[((size_t)b * LL + (t - 1)) * HH + k0 + kq * 4];
            As[kq * 4 + 0][rrow] = av.x;
            As[kq * 4 + 1][rrow] = av.y;
            As[kq * 4 + 2][rrow] = av.z;
            As[kq * 4 + 3][rrow] = av.w;
            float4 bv = *(const float4*)&Wih[(size_t)(n0 + rrow) * HH + k0 + kq * 4];
            Bs[kq * 4 + 0][rrow] = bv.x;
            Bs[kq * 4 + 1][rrow] = bv.y;
            Bs[kq * 4 + 2][rrow] = bv.z;
            Bs[kq * 4 + 3][rrow] = bv.w;
        }
        __syncthreads();
#pragma unroll
        for (int kk = 0; kk < 16; kk++) {
            float4 a0 = *(const float4*)&As[kk][ty * 8];
            float4 a1 = *(const float4*)&As[kk][ty * 8 + 4];
            float4 b0 = *(const float4*)&Bs[kk][tx * 8];
            float4 b1 = *(const float4*)&Bs[kk][tx * 8 + 4];
            float am[8] = {a0.x, a0.y, a0.z, a0.w, a1.x, a1.y, a1.z, a1.w};
            float bn[8] = {b0.x, b0.y, b0.z, b0.w, b1.x, b1.y, b1.z, b1.w};
#pragma unroll
            for (int i = 0; i < 8; i++)
#pragma unroll
                for (int j = 0; j < 8; j++) acc[i][j] = fmaf(am[i], bn[j], acc[i][j]);
        }
        __syncthreads();
    }
    float4 bv0 = *(const float4*)&bias[n0 + tx * 8];
    float4 bv1 = *(const float4*)&bias[n0 + tx * 8 + 4];
#pragma unroll
    for (int i = 0; i < 8; i++) {
        int m = m0 + ty * 8 + i;
        if (m < TT * BB) {
            float4 o0 = make_float4(acc[i][0] + bv0.x, acc[i][1] + bv0.y,
                                    acc[i][2] + bv0.z, acc[i][3] + bv0.w);
            float4 o1 = make_float4(acc[i][4] + bv1.x, acc[i][5] + bv1.y,
                                    acc[i][6] + bv1.z, acc[i][7] + bv1.w);
            *(float4*)&xp[(size_t)m * G4 + n0 + tx * 8] = o0;
            *(float4*)&xp[(size_t)m * G4 + n0 + tx * 8 + 4] = o1;
        }
    }
}

__device__ __forceinline__ float sigm_(float x) { return 1.f / (1.f + __expf(-x)); }
__device__ __forceinline__ float tanh_(float x) {
    float xc = fminf(fmaxf(x, -15.f), 15.f);
    float e = __expf(-2.f * xc);
    return (1.f - e) / (1.f + e);
}

// ---------------- K2: persistent bidirectional LSTM recurrence ----------------
// 64 blocks: 0..31 fwd, 32..63 bwd. Block g owns 16 hidden units (64 W_hh rows,
// register-resident). Exchange via PLAIN sc0/sc1 (agent-coherent, cache-bypass)
// vector loads/stores in inline asm — no fences, no atomics (R3 lesson: HIP
// 64-bit agent atomics lowered to serialized per-lane RMWs; 19.5us/step).
__global__ __launch_bounds__(256, 1) void k2_lstm(
    const float* __restrict__ WhhF, const float* __restrict__ WhhB,
    const float* __restrict__ outbuf, float* __restrict__ ws) {
    __shared__ f32x4_ hlds4[512];     // h staged, XOR-swizzled f4 layout
    __shared__ float g_lds[64][4];
    __shared__ float clds[16][4];

    int bid = blockIdx.x;
    int dir = bid >> 5;
    int g = bid & 31;
    int j0 = g * 16;
    const float* Whh = dir ? WhhB : WhhF;
    const float* xp = outbuf + XPROJ_OFF + (size_t)dir * XPROJ_PER_DIR;
    float* Hbase = ws + (dir ? HB_OFF : HF_OFF);
    int* flg = (int*)(ws + FLG_OFF) + dir * 131 * 32;
    int tid = threadIdx.x;
    int rg = tid >> 5, cc = tid & 31;  // 8 row-groups x 32 col-chunks
    int lane = tid & 63;

    // ---- weights: thread owns 8 rows x 16 cols of the block's 64x512 slice
    float w[8][16];
#pragma unroll
    for (int i = 0; i < 8; i++) {
        int rl = rg * 8 + i;
        int q = rl >> 4, u = rl & 15;
        const float* wrow = Whh + (size_t)(q * 512 + j0 + u) * HH + cc * 16;
#pragma unroll
        for (int c4 = 0; c4 < 4; c4++) {
            float4 vv = *(const float4*)&wrow[c4 * 4];
            w[i][c4 * 4 + 0] = vv.x;
            w[i][c4 * 4 + 1] = vv.y;
            w[i][c4 * 4 + 2] = vv.z;
            w[i][c4 * 4 + 3] = vv.w;
        }
    }

    int u_ = (tid >> 2) & 15, b_ = tid & 3;  // combine-thread mapping (tid<64)
    int brow_s = tid >> 6;
    int q0 = (2 * tid) & 127;
    int xw = (q0 >> 2) & 7;

    for (int s = 0; s < TT; s++) {
        int t = dir ? (129 - s) : s;
        int slot_in = dir ? (t + 1) : t;
        int slot_out = dir ? t : (t + 1);

        // prefetch xproj gates (independent of h; normal cached loads)
        float xq[4] = {0.f, 0.f, 0.f, 0.f};
        if (tid < 64) {
#pragma unroll
            for (int q = 0; q < 4; q++)
                xq[q] = xp[((size_t)t * BB + b_) * G4 + q * 512 + j0 + u_];
        }

        float vred = 0.f;
        if (s > 0) {
            // ---- poll all 32 producer flags in ONE 64-lane sc1 load per iter
            const int* fp = flg + slot_in * 32 + (lane & 31);
            int fv;
            do {
                asm volatile(
                    "global_load_dword %0, %1, off sc0 sc1\n\t"
                    "s_waitcnt vmcnt(0)"
                    : "=v"(fv) : "v"(fp) : "memory");
            } while (!__all(fv != 0));

            // ---- stage h (8 KB) into LDS via coalesced sc1 dwordx4 loads
            {
                const float* hsrc = Hbase + (size_t)slot_in * G4 + 8 * tid;
                f32x4_ a, b2;
                asm volatile(
                    "global_load_dwordx4 %0, %2, off sc0 sc1\n\t"
                    "global_load_dwordx4 %1, %3, off sc0 sc1\n\t"
                    "s_waitcnt vmcnt(0)"
                    : "=&v"(a), "=&v"(b2)
                    : "v"(hsrc), "v"(hsrc + 4)
                    : "memory");
                hlds4[brow_s * 128 + (q0 ^ xw)] = a;
                hlds4[brow_s * 128 + ((q0 + 1) ^ xw)] = b2;
            }
            __syncthreads();

            // ---- dot: v[i*4+b] partial over this thread's 16 cols
            float v[32];
#pragma unroll
            for (int i = 0; i < 32; i++) v[i] = 0.f;
#pragma unroll
            for (int b = 0; b < 4; b++) {
#pragma unroll
                for (int c4 = 0; c4 < 4; c4++) {
                    int quad = cc * 4 + c4;
                    int qs = quad ^ (cc & 7);
                    f32x4_ h4 = hlds4[b * 128 + qs];
#pragma unroll
                    for (int i = 0; i < 8; i++) {
                        float* pv = &v[i * 4 + b];
                        *pv = fmaf(w[i][c4 * 4 + 0], h4.x, *pv);
                        *pv = fmaf(w[i][c4 * 4 + 1], h4.y, *pv);
                        *pv = fmaf(w[i][c4 * 4 + 2], h4.z, *pv);
                        *pv = fmaf(w[i][c4 * 4 + 3], h4.w, *pv);
                    }
                }
            }
            // ---- halving reduce over 32 lanes: lane cc ends with value idx cc
            {
                int n = 16;
#pragma unroll
                for (int m = 16; m >= 1; m >>= 1) {
                    bool up = (cc & m) != 0;
#pragma unroll
                    for (int j = 0; j < 16; j++) {
                        if (j < n) {
                            float send = up ? v[j] : v[j + n];
                            float recv = __shfl_xor(send, m, 64);
                            v[j] = (up ? v[j + n] : v[j]) + recv;
                        }
                    }
                    n >>= 1;
                }
            }
            vred = v[0];
        }
        // lane cc of rg holds gate value (row rg*8 + (cc>>2), batch cc&3)
        g_lds[rg * 8 + (cc >> 2)][cc & 3] = vred;
        __syncthreads();

        // ---- gates + state update + publish (wave 0: 16 units x 4 batches)
        if (tid < 64) {
            float gv[4];
#pragma unroll
            for (int q = 0; q < 4; q++) gv[q] = g_lds[q * 16 + u_][b_] + xq[q];
            float cprev = (s == 0) ? 0.f : clds[u_][b_];
            float si = sigm_(gv[0]);
            float sf = sigm_(gv[1]);
            float tg = tanh_(gv[2]);
            float so = sigm_(gv[3]);
            float cn = sf * cprev + si * tg;
            clds[u_][b_] = cn;
            float hval = so * tanh_(cn);
            float* hp = Hbase + (size_t)slot_out * G4 + b_ * HH + j0 + u_;
            asm volatile("global_store_dword %0, %1, off sc0 sc1"
                         :: "v"(hp), "v"(hval) : "memory");
            // release: drain h stores to the coherence point, then set own flag
            asm volatile("s_waitcnt vmcnt(0)" ::: "memory");
            if (tid == 0) {
                int one = 1;
                int* fo = flg + slot_out * 32 + g;
                asm volatile("global_store_dword %0, %1, off sc0 sc1"
                             :: "v"(fo), "v"(one) : "memory");
            }
        }
        // no trailing barrier: next-step poll (requires OWN flag, set by wave0
        // after its g_lds reads) orders waves 1-3 behind wave0's gate phase.
    }
}

// ---------------- K3: pairwise span diffs -> output ----------------
__global__ __launch_bounds__(256) void k3_out(const float* __restrict__ ws,
                                              float* __restrict__ out) {
    const float* HF = ws + HF_OFF;
    const float* HB = ws + HB_OFF;
    size_t idx = (size_t)blockIdx.x * 256 + threadIdx.x;
    const size_t total = 16777216;  // f4 count
    const size_t stride = (size_t)2048 * 256;
    for (; idx < total; idx += stride) {
        int c4 = idx & 255;
        int b = (idx >> 8) & 3;
        int k = (idx >> 10) & 127;
        int i = (int)(idx >> 17);
        f32x4_ res = (f32x4_)0.f;
        if (i >= 1 && k > i && k <= 126) {
            int c0 = c4 * 4;
            if (c0 < 512) {
                const f32x4_ a = *(const f32x4_*)&HF[(size_t)(k + 1) * G4 + b * HH + c0];
                const f32x4_ c = *(const f32x4_*)&HF[(size_t)(i + 1) * G4 + b * HH + c0];
                res = a - c;
            } else {
                int cd = c0 - 512;
                const f32x4_ a = *(const f32x4_*)&HB[(size_t)(i + 1) * G4 + b * HH + cd];
                const f32x4_ c = *(const f32x4_*)&HB[(size_t)(k + 1) * G4 + b * HH + cd];
                res = a - c;
            }
        }
        __builtin_nontemporal_store(res, (f32x4_*)&out[idx * 4]);
    }
}

extern "C" void kernel_launch(void* const* d_in, const int* in_sizes, int n_in,
                              void* d_out, int out_size, void* d_ws, size_t ws_size,
                              hipStream_t stream) {
    const float* wr   = (const float*)d_in[0];
    const float* WihF = (const float*)d_in[1];
    const float* WhhF = (const float*)d_in[2];
    const float* bF   = (const float*)d_in[3];
    const float* WihB = (const float*)d_in[4];
    const float* WhhB = (const float*)d_in[5];
    const float* bB   = (const float*)d_in[6];
    float* out = (float*)d_out;
    float* ws = (float*)d_ws;

    k0_init<<<1, 256, 0, stream>>>(ws);
    k1_xproj<<<160, 256, 0, stream>>>(wr, WihF, bF, WihB, bB, out);
    k2_lstm<<<64, 256, 0, stream>>>(WhhF, WhhB, out, ws);
    k3_out<<<2048, 256, 0, stream>>>(ws, out);
}

// Round 6
// 2800.306 us; speedup vs baseline: 1.0345x; 1.0345x over previous
//
#include <hip/hip_runtime.h>
#include <math.h>

#define HH 512
#define LL 128
#define BB 4
#define TT 130            // L + 2
#define G4 2048           // 4*H

typedef float f32x4_ __attribute__((ext_vector_type(4)));
typedef int   i32x2_ __attribute__((ext_vector_type(2)));

// ---- ws layout (float indices) ----
// HF: 131 slots of [B][H] = 131*2048 floats   (history, for K3; plain stores)
// HB: same
// Hx: tagged exchange ring: int2[2 dir][4 ring][32 rec][64 lane] = 131072 B
#define HF_OFF 0
#define HB_OFF 268288
#define HX_OFF 536576
// xproj lives in the TAIL of d_out (K3 overwrites it last): 2 * 130*4*2048 floats
#define XPROJ_PER_DIR (TT * BB * G4)              // 1064960
#define XPROJ_OFF (67108864 - 2 * XPROJ_PER_DIR)  // 64978944

// ---------------- K1: input projection GEMM (both dirs) ----------------
__global__ __launch_bounds__(256) void k1_xproj(
    const float* __restrict__ wr,
    const float* __restrict__ WihF, const float* __restrict__ bF,
    const float* __restrict__ WihB, const float* __restrict__ bB,
    float* __restrict__ outbuf) {
    __shared__ float As[16][132];
    __shared__ float Bs[16][132];
    int bid = blockIdx.x;
    int d = bid / 80;
    int r2 = bid % 80;
    int mt = r2 >> 4, nt = r2 & 15;
    const float* Wih  = d ? WihB : WihF;
    const float* bias = d ? bB : bF;
    float* xp = outbuf + XPROJ_OFF + (size_t)d * XPROJ_PER_DIR;
    int tid = threadIdx.x;
    int ty = tid >> 4, tx = tid & 15;
    int m0 = mt * 128, n0 = nt * 128;

    float acc[8][8];
#pragma unroll
    for (int i = 0; i < 8; i++)
#pragma unroll
        for (int j = 0; j < 8; j++) acc[i][j] = 0.f;

    for (int k0 = 0; k0 < HH; k0 += 16) {
#pragma unroll
        for (int l = tid; l < 512; l += 256) {
            int rrow = l & 127;
            int kq = l >> 7;
            int m = m0 + rrow;
            int t = m >> 2, b = m & 3;
            float4 av = make_float4(0.f, 0.f, 0.f, 0.f);
            if (t >= 1 && t <= 128)
                av = *(const float4*)&wr[((size_t)b * LL + (t - 1)) * HH + k0 + kq * 4];
            As[kq * 4 + 0][rrow] = av.x;
            As[kq * 4 + 1][rrow] = av.y;
            As[kq * 4 + 2][rrow] = av.z;
            As[kq * 4 + 3][rrow] = av.w;
            float4 bv = *(const float4*)&Wih[(size_t)(n0 + rrow) * HH + k0 + kq * 4];
            Bs[kq * 4 + 0][rrow] = bv.x;
            Bs[kq * 4 + 1][rrow] = bv.y;
            Bs[kq * 4 + 2][rrow] = bv.z;
            Bs[kq * 4 + 3][rrow] = bv.w;
        }
        __syncthreads();
#pragma unroll
        for (int kk = 0; kk < 16; kk++) {
            float4 a0 = *(const float4*)&As[kk][ty * 8];
            float4 a1 = *(const float4*)&As[kk][ty * 8 + 4];
            float4 b0 = *(const float4*)&Bs[kk][tx * 8];
            float4 b1 = *(const float4*)&Bs[kk][tx * 8 + 4];
            float am[8] = {a0.x, a0.y, a0.z, a0.w, a1.x, a1.y, a1.z, a1.w};
            float bn[8] = {b0.x, b0.y, b0.z, b0.w, b1.x, b1.y, b1.z, b1.w};
#pragma unroll
            for (int i = 0; i < 8; i++)
#pragma unroll
                for (int j = 0; j < 8; j++) acc[i][j] = fmaf(am[i], bn[j], acc[i][j]);
        }
        __syncthreads();
    }
    float4 bv0 = *(const float4*)&bias[n0 + tx * 8];
    float4 bv1 = *(const float4*)&bias[n0 + tx * 8 + 4];
#pragma unroll
    for (int i = 0; i < 8; i++) {
        int m = m0 + ty * 8 + i;
        if (m < TT * BB) {
            float4 o0 = make_float4(acc[i][0] + bv0.x, acc[i][1] + bv0.y,
                                    acc[i][2] + bv0.z, acc[i][3] + bv0.w);
            float4 o1 = make_float4(acc[i][4] + bv1.x, acc[i][5] + bv1.y,
                                    acc[i][6] + bv1.z, acc[i][7] + bv1.w);
            *(float4*)&xp[(size_t)m * G4 + n0 + tx * 8] = o0;
            *(float4*)&xp[(size_t)m * G4 + n0 + tx * 8 + 4] = o1;
        }
    }
}

__device__ __forceinline__ float sigm_(float x) { return 1.f / (1.f + __expf(-x)); }
__device__ __forceinline__ float tanh_(float x) {
    float xc = fminf(fmaxf(x, -15.f), 15.f);
    float e = __expf(-2.f * xc);
    return (1.f - e) / (1.f + e);
}

// ---------------- K2: persistent bidirectional LSTM recurrence ----------------
// 64 blocks: 0..31 fwd, 32..63 bwd. Block g owns 16 hidden units (64 W_hh rows,
// register-resident). Exchange: DATA-IS-THE-FLAG — each producer lane stores an
// 8-byte (h, tag=slot) atom, fire-and-forget (no waitcnt, no flags, no fences).
// Consumers poll the tagged atoms directly (8-B single-copy atomicity) and
// scatter ready records into LDS. One MALL hop per step instead of three
// (R1/R3/R5 all paid produce-ack + flag-hop + fetch = 10-20us/step).
__global__ __launch_bounds__(256, 1) void k2_lstm(
    const float* __restrict__ WhhF, const float* __restrict__ WhhB,
    const float* __restrict__ outbuf, float* __restrict__ ws) {
    __shared__ __align__(16) float hlds_f[2048];   // h staged, XOR-swizzled f4 layout
    __shared__ float g_lds[64][4];
    __shared__ float clds[16][4];

    int bid = blockIdx.x;
    int dir = bid >> 5;
    int g = bid & 31;
    int j0 = g * 16;
    const float* Whh = dir ? WhhB : WhhF;
    const float* xp = outbuf + XPROJ_OFF + (size_t)dir * XPROJ_PER_DIR;
    float* Hbase = ws + (dir ? HB_OFF : HF_OFF);
    i32x2_* Hx = (i32x2_*)(ws + HX_OFF);
    int tid = threadIdx.x;
    int rg = tid >> 5, cc = tid & 31;  // 8 row-groups x 32 col-chunks
    int lane = tid & 63;
    int wv = tid >> 6;

    // ---- weights: thread owns 8 rows x 16 cols of the block's 64x512 slice
    float w[8][16];
#pragma unroll
    for (int i = 0; i < 8; i++) {
        int rl = rg * 8 + i;
        int q = rl >> 4, u = rl & 15;
        const float* wrow = Whh + (size_t)(q * 512 + j0 + u) * HH + cc * 16;
#pragma unroll
        for (int c4 = 0; c4 < 4; c4++) {
            float4 vv = *(const float4*)&wrow[c4 * 4];
            w[i][c4 * 4 + 0] = vv.x;
            w[i][c4 * 4 + 1] = vv.y;
            w[i][c4 * 4 + 2] = vv.z;
            w[i][c4 * 4 + 3] = vv.w;
        }
    }

    int u_ = (tid >> 2) & 15, b_ = tid & 3;  // combine-thread mapping (tid<64)
    int su = lane >> 2, sb = lane & 3;       // consumer scatter mapping

    for (int s = 0; s < TT; s++) {
        int t = dir ? (129 - s) : s;
        int slot_in = dir ? (t + 1) : t;
        int slot_out = dir ? t : (t + 1);

        // prefetch xproj gates (independent of h; normal cached loads)
        float xq[4] = {0.f, 0.f, 0.f, 0.f};
        if (tid < 64) {
#pragma unroll
            for (int q = 0; q < 4; q++)
                xq[q] = xp[((size_t)t * BB + b_) * G4 + q * 512 + j0 + u_];
        }

        float vred = 0.f;
        if (s > 0) {
            // ---- poll tagged records (this wave owns records wv*8..wv*8+7)
            const i32x2_* rec = Hx + ((size_t)(dir * 4 + (slot_in & 3)) * 32) * 64;
            unsigned ready = 0;
            while (ready != 0xFFu) {
                i32x2_ d0, d1, d2, d3, d4, d5, d6, d7;
#define PLOAD(n) asm volatile("global_load_dwordx2 %0, %1, off sc0 sc1" \
            : "=v"(d##n) : "v"(rec + (wv * 8 + n) * 64 + lane) : "memory")
                PLOAD(0); PLOAD(1); PLOAD(2); PLOAD(3);
                PLOAD(4); PLOAD(5); PLOAD(6); PLOAD(7);
#undef PLOAD
                asm volatile("s_waitcnt vmcnt(0)" ::: "memory");
#define PCHK(n) if (!(ready & (1u << n)) && __all(d##n.y == slot_in)) {      \
                    int r = wv * 8 + n;                                       \
                    int quad = r * 4 + (su >> 2);                             \
                    int qs = quad ^ ((quad >> 2) & 7);                        \
                    hlds_f[(sb * 128 + qs) * 4 + (su & 3)] =                  \
                        __int_as_float(d##n.x);                               \
                    ready |= (1u << n);                                       \
                }
                PCHK(0); PCHK(1); PCHK(2); PCHK(3);
                PCHK(4); PCHK(5); PCHK(6); PCHK(7);
#undef PCHK
            }
            __syncthreads();

            // ---- dot: v[i*4+b] partial over this thread's 16 cols
            float v[32];
#pragma unroll
            for (int i = 0; i < 32; i++) v[i] = 0.f;
            const f32x4_* hlds4 = (const f32x4_*)hlds_f;
#pragma unroll
            for (int b = 0; b < 4; b++) {
#pragma unroll
                for (int c4 = 0; c4 < 4; c4++) {
                    int quad = cc * 4 + c4;
                    int qs = quad ^ (cc & 7);
                    f32x4_ h4 = hlds4[b * 128 + qs];
#pragma unroll
                    for (int i = 0; i < 8; i++) {
                        float* pv = &v[i * 4 + b];
                        *pv = fmaf(w[i][c4 * 4 + 0], h4.x, *pv);
                        *pv = fmaf(w[i][c4 * 4 + 1], h4.y, *pv);
                        *pv = fmaf(w[i][c4 * 4 + 2], h4.z, *pv);
                        *pv = fmaf(w[i][c4 * 4 + 3], h4.w, *pv);
                    }
                }
            }
            // ---- halving reduce over 32 lanes: lane cc ends with value idx cc
            {
                int n = 16;
#pragma unroll
                for (int m = 16; m >= 1; m >>= 1) {
                    bool up = (cc & m) != 0;
#pragma unroll
                    for (int j = 0; j < 16; j++) {
                        if (j < n) {
                            float send = up ? v[j] : v[j + n];
                            float recv = __shfl_xor(send, m, 64);
                            v[j] = (up ? v[j + n] : v[j]) + recv;
                        }
                    }
                    n >>= 1;
                }
            }
            vred = v[0];
        }
        // lane cc of rg holds gate value (row rg*8 + (cc>>2), batch cc&3)
        g_lds[rg * 8 + (cc >> 2)][cc & 3] = vred;
        __syncthreads();
        // hlds_f is free after this barrier: every wave's dot reads completed
        // before its g_lds write; next step's scatter happens after it.

        // ---- gates + state update + publish (wave 0: 16 units x 4 batches)
        if (tid < 64) {
            float gv[4];
#pragma unroll
            for (int q = 0; q < 4; q++) gv[q] = g_lds[q * 16 + u_][b_] + xq[q];
            float cprev = (s == 0) ? 0.f : clds[u_][b_];
            float si = sigm_(gv[0]);
            float sf = sigm_(gv[1]);
            float tg = tanh_(gv[2]);
            float so = sigm_(gv[3]);
            float cn = sf * cprev + si * tg;
            clds[u_][b_] = cn;
            float hval = so * tanh_(cn);
            // history for K3 (plain cached store; kernel boundary publishes it)
            Hbase[(size_t)slot_out * G4 + b_ * HH + j0 + u_] = hval;
            // tagged publish: fire-and-forget, 8-B atom carries its own flag
            i32x2_ pub;
            pub.x = __float_as_int(hval);
            pub.y = slot_out;
            i32x2_* pp = Hx + ((size_t)(dir * 4 + (slot_out & 3)) * 32 + g) * 64 + tid;
            asm volatile("global_store_dwordx2 %0, %1, off sc0 sc1"
                         :: "v"(pp), "v"(pub) : "memory");
        }
        // no waitcnt, no flag, no trailing barrier
    }
}

// ---------------- K3: pairwise span diffs -> output ----------------
__global__ __launch_bounds__(256) void k3_out(const float* __restrict__ ws,
                                              float* __restrict__ out) {
    const float* HF = ws + HF_OFF;
    const float* HB = ws + HB_OFF;
    size_t idx = (size_t)blockIdx.x * 256 + threadIdx.x;
    const size_t total = 16777216;  // f4 count
    const size_t stride = (size_t)2048 * 256;
    for (; idx < total; idx += stride) {
        int c4 = idx & 255;
        int b = (idx >> 8) & 3;
        int k = (idx >> 10) & 127;
        int i = (int)(idx >> 17);
        f32x4_ res = (f32x4_)0.f;
        if (i >= 1 && k > i && k <= 126) {
            int c0 = c4 * 4;
            if (c0 < 512) {
                const f32x4_ a = *(const f32x4_*)&HF[(size_t)(k + 1) * G4 + b * HH + c0];
                const f32x4_ c = *(const f32x4_*)&HF[(size_t)(i + 1) * G4 + b * HH + c0];
                res = a - c;
            } else {
                int cd = c0 - 512;
                const f32x4_ a = *(const f32x4_*)&HB[(size_t)(i + 1) * G4 + b * HH + cd];
                const f32x4_ c = *(const f32x4_*)&HB[(size_t)(k + 1) * G4 + b * HH + cd];
                res = a - c;
            }
        }
        __builtin_nontemporal_store(res, (f32x4_*)&out[idx * 4]);
    }
}

extern "C" void kernel_launch(void* const* d_in, const int* in_sizes, int n_in,
                              void* d_out, int out_size, void* d_ws, size_t ws_size,
                              hipStream_t stream) {
    const float* wr   = (const float*)d_in[0];
    const float* WihF = (const float*)d_in[1];
    const float* WhhF = (const float*)d_in[2];
    const float* bF   = (const float*)d_in[3];
    const float* WihB = (const float*)d_in[4];
    const float* WhhB = (const float*)d_in[5];
    const float* bB   = (const float*)d_in[6];
    float* out = (float*)d_out;
    float* ws = (float*)d_ws;

    k1_xproj<<<160, 256, 0, stream>>>(wr, WihF, bF, WihB, bB, out);
    k2_lstm<<<64, 256, 0, stream>>>(WhhF, WhhB, out, ws);
    k3_out<<<2048, 256, 0, stream>>>(ws, out);
}